// Round 2
// baseline (328.029 us; speedup 1.0000x reference)
//
#include <hip/hip_runtime.h>
#include <hip/hip_bf16.h>

// Problem constants (reference: B=32, S=2048, D=1024, F=512, E=8, GROUP=32 -> 1 group)
#define SS 2048
#define BB 32
#define DD 1024
#define FF 512
#define EE 8

typedef __attribute__((ext_vector_type(8))) short short8;
typedef __attribute__((ext_vector_type(8))) unsigned short ushort8v;
typedef __attribute__((ext_vector_type(4))) unsigned short ushort4v;
typedef __attribute__((ext_vector_type(4))) float f32x4;

__device__ inline unsigned short f2bf(float f) {
  union { float f; unsigned u; } v; v.f = f;
  return (unsigned short)((v.u + 0x7FFFu + ((v.u >> 16) & 1u)) >> 16);
}
__device__ inline float bf2f(unsigned short h) {
  union { unsigned u; float f; } v; v.u = ((unsigned)h) << 16;
  return v.f;
}

// ---------------- transpose + fp32->bf16 cast: in (E,K,N) f32 -> out (E,N,K) bf16
__global__ __launch_bounds__(256) void transpose_bf16(
    const float* __restrict__ in, unsigned short* __restrict__ out, int K, int N) {
  __shared__ float tile[32][33];
  int e = blockIdx.z;
  const float* inp = in + (size_t)e * K * N;
  unsigned short* outp = out + (size_t)e * K * N;
  int k0 = blockIdx.x * 32, n0 = blockIdx.y * 32;
  int tx = threadIdx.x;   // 0..31
  int ty = threadIdx.y;   // 0..7
#pragma unroll
  for (int i = 0; i < 4; i++) {
    int k = ty + i * 8;
    tile[k][tx] = inp[(size_t)(k0 + k) * N + n0 + tx];
  }
  __syncthreads();
#pragma unroll
  for (int i = 0; i < 4; i++) {
    int n = ty + i * 8;
    outp[(size_t)(n0 + n) * K + k0 + tx] = f2bf(tile[tx][n]);
  }
}

// ---------------- controller logits + softmax over 32 tokens + merged tokens
// one block per s; 512 threads = 8 waves
// Phase A: wave w owns tokens 4w..4w+3; lane owns 16 d (lane*4 + i*256).
//          ctrl fragments hoisted into registers; x staged to LDS bf16 on the fly.
// Phase B: wave-parallel softmax over the 32 tokens (lanes 0..31 of wave 0).
// Phase C: thread owns d = {2t, 2t+1}; reads bf16 x from LDS; 16 acc chains.
__global__ __launch_bounds__(512) void ctrl_merge(
    const float* __restrict__ x,          // (B,S,D) f32
    const float* __restrict__ ctrl,       // (D,E) f32
    unsigned short* __restrict__ merged,  // (S,E,D) bf16
    float* __restrict__ mw) {             // (S,B,E) f32
  int s = blockIdx.x;
  int t = threadIdx.x;
  int lane = t & 63, w = t >> 6;

  __shared__ float cs[EE][DD];              // 32 KiB, ctrl transposed [e][d]
  __shared__ unsigned short xs[BB][DD];     // 64 KiB, tokens in bf16
  __shared__ float wl[BB][EE];              // logits -> weights in place

  // ctrl (D,E) -> cs[e][d], conflict-free writes (d-major per thread)
  for (int i = t; i < DD * EE; i += 512) {
    int e2 = i >> 10, d = i & 1023;
    cs[e2][d] = ctrl[(size_t)d * EE + e2];
  }
  __syncthreads();

  // ---- phase A: logits, with x->LDS bf16 staging
  float acc[4][8] = {};
#pragma unroll
  for (int i = 0; i < 4; i++) {
    int dbase = lane * 4 + i * 256;
    float4 c4[8];
#pragma unroll
    for (int e2 = 0; e2 < 8; e2++) c4[e2] = *(const float4*)&cs[e2][dbase];
#pragma unroll
    for (int kk = 0; kk < 4; kk++) {
      int k = (w << 2) + kk;
      float4 xv = *(const float4*)&x[((size_t)k * SS + s) * DD + dbase];
      ushort4v pv;
      pv[0] = f2bf(xv.x); pv[1] = f2bf(xv.y); pv[2] = f2bf(xv.z); pv[3] = f2bf(xv.w);
      *(ushort4v*)&xs[k][dbase] = pv;
#pragma unroll
      for (int e2 = 0; e2 < 8; e2++)
        acc[kk][e2] += xv.x * c4[e2].x + xv.y * c4[e2].y + xv.z * c4[e2].z + xv.w * c4[e2].w;
    }
  }
  // butterfly reduce over the 64 lanes
#pragma unroll
  for (int off = 1; off < 64; off <<= 1)
#pragma unroll
    for (int kk = 0; kk < 4; kk++)
#pragma unroll
      for (int e2 = 0; e2 < 8; e2++)
        acc[kk][e2] += __shfl_xor(acc[kk][e2], off, 64);
  if (lane == 0) {
#pragma unroll
    for (int kk = 0; kk < 4; kk++)
#pragma unroll
      for (int e2 = 0; e2 < 8; e2++)
        wl[(w << 2) + kk][e2] = acc[kk][e2];
  }
  __syncthreads();

  // ---- phase B: softmax over tokens (k) per expert column, wave-parallel
  if (t < 32) {
    float lgv[8], mx[8], p[8], sm[8];
#pragma unroll
    for (int e2 = 0; e2 < 8; e2++) { lgv[e2] = wl[t][e2]; mx[e2] = lgv[e2]; }
#pragma unroll
    for (int off = 1; off < 32; off <<= 1)
#pragma unroll
      for (int e2 = 0; e2 < 8; e2++)
        mx[e2] = fmaxf(mx[e2], __shfl_xor(mx[e2], off, 64));
#pragma unroll
    for (int e2 = 0; e2 < 8; e2++) { p[e2] = __expf(lgv[e2] - mx[e2]); sm[e2] = p[e2]; }
#pragma unroll
    for (int off = 1; off < 32; off <<= 1)
#pragma unroll
      for (int e2 = 0; e2 < 8; e2++)
        sm[e2] += __shfl_xor(sm[e2], off, 64);
    float wv[8];
#pragma unroll
    for (int e2 = 0; e2 < 8; e2++) { wv[e2] = p[e2] / sm[e2]; wl[t][e2] = wv[e2]; }
    float4 mv0 = {wv[0], wv[1], wv[2], wv[3]};
    float4 mv1 = {wv[4], wv[5], wv[6], wv[7]};
    float* mwp = &mw[((size_t)s * BB + t) * EE];
    *(float4*)mwp = mv0;
    *(float4*)(mwp + 4) = mv1;
  }
  __syncthreads();

  // ---- phase C: merged[e][d] = sum_k w[k][e] * x[k][d], thread owns d = 2t, 2t+1
  int d0 = t << 1;
  float a0[8] = {}, a1[8] = {};
#pragma unroll 4
  for (int k = 0; k < 32; k++) {
    unsigned xv = *(const unsigned*)&xs[k][d0];
    float x0 = bf2f((unsigned short)xv);
    float x1 = bf2f((unsigned short)(xv >> 16));
    float4 wA = *(const float4*)&wl[k][0];
    float4 wB = *(const float4*)&wl[k][4];
    a0[0] += wA.x * x0; a1[0] += wA.x * x1;
    a0[1] += wA.y * x0; a1[1] += wA.y * x1;
    a0[2] += wA.z * x0; a1[2] += wA.z * x1;
    a0[3] += wA.w * x0; a1[3] += wA.w * x1;
    a0[4] += wB.x * x0; a1[4] += wB.x * x1;
    a0[5] += wB.y * x0; a1[5] += wB.y * x1;
    a0[6] += wB.z * x0; a1[6] += wB.z * x1;
    a0[7] += wB.w * x0; a1[7] += wB.w * x1;
  }
#pragma unroll
  for (int e2 = 0; e2 < 8; e2++) {
    unsigned pm = (unsigned)f2bf(a0[e2]) | ((unsigned)f2bf(a1[e2]) << 16);
    *(unsigned*)&merged[((size_t)s * EE + e2) * DD + d0] = pm;
  }
}

// ---------------- bf16 MFMA GEMM, B-transposed weights (both operands k-contiguous)
// A: (S, E, K) bf16, expert slice rows stride E*K ; Bt: (E, N, K) bf16 ; C: (S, E, N) bf16
// grid: (S/128, N/128, E), 256 threads = 4 waves (2x2), wave tile 64x64, 16x16x32 frags
template <int RELU>
__global__ __launch_bounds__(256) void gemm_bt(
    const unsigned short* __restrict__ A, const unsigned short* __restrict__ Bt,
    unsigned short* __restrict__ C, int K, int N) {
  int e = blockIdx.z;
  int m0 = blockIdx.x * 128;
  int n0 = blockIdx.y * 128;
  const int lda = EE * K;
  const unsigned short* Ae = A + (size_t)e * K;
  const unsigned short* Be = Bt + (size_t)e * N * K;

  __shared__ __align__(16) unsigned short As[128][40];  // +8 pad: bank-conflict-free b128
  __shared__ __align__(16) unsigned short Bs[128][40];

  int t = threadIdx.x;
  int lane = t & 63, w = t >> 6;
  int wm = w >> 1, wn = w & 1;
  int lr = lane & 15;     // fragment row
  int kh = lane >> 4;     // k-half index: k-offset kh*8

  f32x4 acc[4][4] = {};

  for (int kt = 0; kt < K; kt += 32) {
    // stage A and Bt tiles: 128x32 bf16 each = 512 ushort8 chunks, 2 per thread
#pragma unroll
    for (int i = 0; i < 2; i++) {
      int o = t + i * 256;          // 0..511
      int r = o >> 2, c8 = (o & 3) * 8;
      ushort8v va = *(const ushort8v*)&Ae[(size_t)(m0 + r) * lda + kt + c8];
      *(ushort8v*)&As[r][c8] = va;
      ushort8v vb = *(const ushort8v*)&Be[(size_t)(n0 + r) * K + kt + c8];
      *(ushort8v*)&Bs[r][c8] = vb;
    }
    __syncthreads();

    short8 af[4], bfr[4];
#pragma unroll
    for (int mi = 0; mi < 4; mi++)
      af[mi] = *(const short8*)&As[wm * 64 + mi * 16 + lr][kh * 8];
#pragma unroll
    for (int ni = 0; ni < 4; ni++)
      bfr[ni] = *(const short8*)&Bs[wn * 64 + ni * 16 + lr][kh * 8];
#pragma unroll
    for (int mi = 0; mi < 4; mi++)
#pragma unroll
      for (int ni = 0; ni < 4; ni++)
        acc[mi][ni] = __builtin_amdgcn_mfma_f32_16x16x32_bf16(af[mi], bfr[ni], acc[mi][ni], 0, 0, 0);
    __syncthreads();
  }

  // epilogue: C/D layout col=lane&15, row=(lane>>4)*4+reg  [verified m89]
  int rb = (lane >> 4) * 4;
  int cb = lane & 15;
#pragma unroll
  for (int mi = 0; mi < 4; mi++)
#pragma unroll
    for (int ni = 0; ni < 4; ni++)
#pragma unroll
      for (int r = 0; r < 4; r++) {
        float v = acc[mi][ni][r];
        if (RELU) v = fmaxf(v, 0.f);
        int m = m0 + wm * 64 + mi * 16 + rb + r;
        int n = n0 + wn * 64 + ni * 16 + cb;
        C[(size_t)m * (EE * N) + (size_t)e * N + n] = f2bf(v);
      }
}

// ---------------- emit: out[b,s,d] = sum_e mw[s,b,e] * eo[s,e,d]
// 256 threads; thread owns d = 4t..4t+3; float4 stores
__global__ __launch_bounds__(256) void emit_out(
    const unsigned short* __restrict__ eo,  // (S,E,D) bf16
    const float* __restrict__ mw,           // (S,B,E) f32
    float* __restrict__ out) {              // (B,S,D) f32
  int s = blockIdx.x;
  int t = threadIdx.x;
  __shared__ float wsm[BB][EE];
  wsm[t >> 3][t & 7] = mw[(size_t)s * BB * EE + t];
  __syncthreads();
  int d0 = t * 4;
  float ev[EE][4];
#pragma unroll
  for (int e2 = 0; e2 < 8; e2++) {
    ushort4v v = *(const ushort4v*)&eo[((size_t)s * EE + e2) * DD + d0];
    ev[e2][0] = bf2f(v[0]); ev[e2][1] = bf2f(v[1]);
    ev[e2][2] = bf2f(v[2]); ev[e2][3] = bf2f(v[3]);
  }
  for (int b = 0; b < BB; b++) {
    float o0 = 0.f, o1 = 0.f, o2 = 0.f, o3 = 0.f;
#pragma unroll
    for (int e2 = 0; e2 < 8; e2++) {
      float we = wsm[b][e2];
      o0 += we * ev[e2][0]; o1 += we * ev[e2][1];
      o2 += we * ev[e2][2]; o3 += we * ev[e2][3];
    }
    float4 ov = {o0, o1, o2, o3};
    *(float4*)&out[((size_t)b * SS + s) * DD + d0] = ov;
  }
}

extern "C" void kernel_launch(void* const* d_in, const int* in_sizes, int n_in,
                              void* d_out, int out_size, void* d_ws, size_t ws_size,
                              hipStream_t stream) {
  const float* x = (const float*)d_in[0];        // (32, 2048, 1024)
  const float* lin1 = (const float*)d_in[1];     // (8, 1024, 512)
  const float* lin2 = (const float*)d_in[2];     // (8, 512, 1024)
  const float* ctrl = (const float*)d_in[3];     // (1024, 8)
  float* out = (float*)d_out;

  char* ws = (char*)d_ws;
  size_t off = 0;
  unsigned short* lin1t = (unsigned short*)(ws + off); off += (size_t)EE * DD * FF * 2;  // (E,F,D) 8 MiB
  unsigned short* lin2t = (unsigned short*)(ws + off); off += (size_t)EE * FF * DD * 2;  // (E,D,F) 8 MiB
  unsigned short* merged = (unsigned short*)(ws + off); off += (size_t)SS * EE * DD * 2; // 32 MiB
  unsigned short* hbuf = (unsigned short*)(ws + off); off += (size_t)SS * EE * FF * 2;   // 16 MiB
  unsigned short* eo = (unsigned short*)(ws + off); off += (size_t)SS * EE * DD * 2;     // 32 MiB
  float* mw = (float*)(ws + off); off += (size_t)SS * BB * EE * 4;                       // 2 MiB

  dim3 tb(32, 8);
  // lin1 (E, K=D, N=F) -> lin1t (E, F, D)
  transpose_bf16<<<dim3(DD / 32, FF / 32, EE), tb, 0, stream>>>(lin1, lin1t, DD, FF);
  // lin2 (E, K=F, N=D) -> lin2t (E, D, F)
  transpose_bf16<<<dim3(FF / 32, DD / 32, EE), tb, 0, stream>>>(lin2, lin2t, FF, DD);

  ctrl_merge<<<SS, 512, 0, stream>>>(x, ctrl, merged, mw);

  // h = relu(merged @ lin1): M=S per expert, K=D, N=F
  gemm_bt<1><<<dim3(SS / 128, FF / 128, EE), 256, 0, stream>>>(merged, lin1t, hbuf, DD, FF);
  // eo = h @ lin2: K=F, N=D
  gemm_bt<0><<<dim3(SS / 128, DD / 128, EE), 256, 0, stream>>>(hbuf, lin2t, eo, FF, DD);

  emit_out<<<SS, 256, 0, stream>>>(eo, mw, out);
}